// Round 9
// baseline (8283.338 us; speedup 1.0000x reference)
//
#include <hip/hip_runtime.h>
#include <hip/hip_bf16.h>
#include <stdint.h>

typedef unsigned int uint;
typedef unsigned long long u64;

#define T_STEPS 128
#define BQ 16
#define HID 512
#define NSLOT 1024
#define MD 64
#define VOCAB 32000
#define BETA 1.000001f
#define EPSN 1e-8f

#define NB_PROJ 128
#define NB_BATCH 16
#define NB_REC (NB_PROJ + NB_BATCH)      // 144

// flag lines (128B apart): [0..15] hgen, [32..159] kgen, [160..287] ggen
#define F_H(b) (((b))*32)
#define F_K(w) ((32+(w))*32)
#define F_G(w) ((160+(w))*32)
#define NFLAGS 288

// agent-coherent (bypass L1/L2) ops; batched waitcnt (+sched_barrier, rule #18)
#define AL4(dst, p) asm volatile("global_load_dwordx4 %0, %1, off sc0 sc1" : "=v"(dst) : "v"(p))
#define AWAIT() do { asm volatile("s_waitcnt vmcnt(0)" ::: "memory"); __builtin_amdgcn_sched_barrier(0); } while(0)

__device__ __forceinline__ float sigm(float x){ return 1.f/(1.f+expf(-x)); }
__device__ __forceinline__ void astoref(float* p, float v){
  __hip_atomic_store(p, v, __ATOMIC_RELAXED, __HIP_MEMORY_SCOPE_AGENT);
}
__device__ __forceinline__ void astoreu32(uint* p, uint v){
  __hip_atomic_store(p, v, __ATOMIC_RELAXED, __HIP_MEMORY_SCOPE_AGENT);
}
__device__ __forceinline__ uint aloadu32(const uint* p){
  return __hip_atomic_load((uint*)p, __ATOMIC_RELAXED, __HIP_MEMORY_SCOPE_AGENT);
}
__device__ __forceinline__ void poll1(const uint* p, uint gen){
  while (aloadu32(p) < gen) __builtin_amdgcn_s_sleep(1);
}
__device__ __forceinline__ void arrive1(uint* line, uint gen){
  asm volatile("s_waitcnt vmcnt(0)" ::: "memory");
  __syncthreads();
  if (threadIdx.x == 0) astoreu32(line, gen);
}

// pack (score, slot): u64 max == (max value, min slot on ties) — matches lax.top_k
__device__ __forceinline__ u64 packsc(float v, int slot){
  uint u = __float_as_uint(v);
  u = (u & 0x80000000u) ? ~u : (u | 0x80000000u);
  return ((u64)u << 10) | (u64)(1023 - slot);
}
__device__ __forceinline__ float unpackval(u64 p){
  uint u = (uint)(p >> 10);
  uint bits = (u & 0x80000000u) ? (u & 0x7fffffffu) : ~u;
  return __uint_as_float(bits);
}
__device__ __forceinline__ int unpackslot(u64 p){ return 1023 - (int)(p & 1023u); }

// ---------------- pre-kernels ----------------
__global__ __launch_bounds__(256) void prep_emb(const float* __restrict__ E,
                                                const int* __restrict__ seq,
                                                float* __restrict__ EMB){
  int m = blockIdx.x, t = m >> 4, b = m & 15;
  int x = seq[b*T_STEPS + t];
  EMB[(size_t)m*256 + threadIdx.x] = E[(size_t)x*256 + threadIdx.x];
}

// G_emb[m][p] packed p=u*4+g, r=g*512+u
__global__ __launch_bounds__(256) void gemm_emb(const float* __restrict__ A,
                                                const float* __restrict__ W_ih,
                                                const float* __restrict__ b_ih,
                                                const float* __restrict__ b_hh,
                                                float* __restrict__ C){
  __shared__ __align__(16) float As[16*68];
  __shared__ __align__(16) float Bs[16*68];
  int mt = blockIdx.x & 31, nt = blockIdx.x >> 5;
  int m0 = mt*64, n0 = nt*64;
  int tx = threadIdx.x & 15, ty = threadIdx.x >> 4;
  float acc[4][4] = {};
  for (int k0 = 0; k0 < 256; k0 += 16){
    int mm = threadIdx.x >> 2, kq = (threadIdx.x & 3)*4;
    float4 a = *(const float4*)(A + (size_t)(m0+mm)*256 + k0 + kq);
    As[(kq+0)*68+mm]=a.x; As[(kq+1)*68+mm]=a.y; As[(kq+2)*68+mm]=a.z; As[(kq+3)*68+mm]=a.w;
    int pp = n0 + mm;
    int r = (pp & 3)*512 + (pp >> 2);
    float4 bv = *(const float4*)(W_ih + (size_t)r*320 + k0 + kq);
    Bs[(kq+0)*68+mm]=bv.x; Bs[(kq+1)*68+mm]=bv.y; Bs[(kq+2)*68+mm]=bv.z; Bs[(kq+3)*68+mm]=bv.w;
    __syncthreads();
    #pragma unroll
    for (int kk = 0; kk < 16; ++kk){
      float4 av = *(const float4*)(As + kk*68 + ty*4);
      float4 bb = *(const float4*)(Bs + kk*68 + tx*4);
      float aa[4] = {av.x,av.y,av.z,av.w};
      float bv2[4] = {bb.x,bb.y,bb.z,bb.w};
      #pragma unroll
      for (int i = 0; i < 4; ++i)
        #pragma unroll
        for (int j = 0; j < 4; ++j)
          acc[i][j] = fmaf(aa[i], bv2[j], acc[i][j]);
    }
    __syncthreads();
  }
  #pragma unroll
  for (int i = 0; i < 4; ++i){
    int m = m0 + ty*4 + i;
    #pragma unroll
    for (int j = 0; j < 4; ++j){
      int pp = n0 + tx*4 + j;
      int r = (pp & 3)*512 + (pp >> 2);
      C[(size_t)m*2048 + pp] = acc[i][j] + b_ih[r] + b_hh[r];
    }
  }
}

// WT[k][p] = W_ih[r(p)][256+k]  (packed-p rv-weight transpose)
__global__ __launch_bounds__(256) void make_wrvT(const float* __restrict__ W_ih,
                                                 float* __restrict__ WT){
  int idx = blockIdx.x*256 + threadIdx.x;   // 0..131071
  int k = idx >> 11, p = idx & 2047;
  int r = (p & 3)*512 + (p >> 2);
  WT[idx] = W_ih[(size_t)r*320 + 256 + k];
}

// ---------------- the 2-hop recurrence (144 WGs; R5-proven roles, gemm excised) ----------------
// blocks [0,128): proj/gate WGs; [128,144): batch WGs
__global__ __launch_bounds__(256, 2) void recur_kernel(
    const float* __restrict__ W_hh, const float* __restrict__ WT,
    const float* __restrict__ W_rk, const float* __restrict__ b_rk,
    const float* __restrict__ W_wk, const float* __restrict__ b_wk,
    const float* __restrict__ W_wv, const float* __restrict__ b_wv,
    const float* __restrict__ W_er, const float* __restrict__ b_er,
    const float* __restrict__ G_emb, float* __restrict__ H_all,
    float* __restrict__ mem_row, float* __restrict__ memT,
    float* __restrict__ projbuf, float* __restrict__ gp_g,
    uint* __restrict__ arrv)
{
  __shared__ __align__(16) float smem[12384];
  const int tid = threadIdx.x;
  const int wg  = blockIdx.x;

  if (wg < NB_PROJ){
    // =================== PROJ / GATE role ===================
    float* hs = smem;              // [16][516]
    float* Ws = smem + 8256;       // [8][516]
    const int p1_b = tid >> 4, p1_col = tid & 15;
    const int pcol = wg*16 + p1_col;
    const int rrow = (pcol & 3)*512 + (pcol >> 2);
    const int msel = wg >> 5, col0 = (wg & 31)*8;
    const float* Wm  = (msel==0)? W_rk : (msel==1)? W_wk : (msel==2)? W_wv : W_er;
    const float* bmp = (msel==0)? b_rk : (msel==1)? b_wk : (msel==2)? b_wv : b_er;
    for (int i = tid; i < 8*HID; i += 256){
      int k = i >> 3, j = i & 7;
      Ws[j*516 + k] = Wm[(size_t)k*256 + col0 + j];
    }
    #pragma clang loop unroll(disable)
    for (int t = 0; t < T_STEPS-1; ++t){
      if (tid < 16) poll1(arrv + F_H(tid), (uint)(t+1));
      __syncthreads();
      const float4* hsrc = (const float4*)(H_all + (size_t)t*BQ*HID);
      for (int i = tid; i < 2048; i += 256){
        int b = i >> 7, q = i & 127;
        *(float4*)(hs + b*516 + q*4) = hsrc[i];   // fresh addresses each t: normal loads OK
      }
      __syncthreads();
      {  // projections
        int b = tid >> 4, o2 = (tid & 15) >> 1, half = tid & 1;
        const float4* wp = (const float4*)(Ws + o2*516 + half*256);
        const float4* xp = (const float4*)(hs + b*516 + half*256);
        float a0 = 0.f, a1 = 0.f;
        #pragma unroll 4
        for (int k = 0; k < 64; k += 2){
          float4 w = wp[k], x = xp[k];
          a0=fmaf(w.x,x.x,a0); a0=fmaf(w.y,x.y,a0); a0=fmaf(w.z,x.z,a0); a0=fmaf(w.w,x.w,a0);
          w = wp[k+1]; x = xp[k+1];
          a1=fmaf(w.x,x.x,a1); a1=fmaf(w.y,x.y,a1); a1=fmaf(w.z,x.z,a1); a1=fmaf(w.w,x.w,a1);
        }
        float acc = a0 + a1;
        float other = __shfl_xor(acc, 1);
        if (half == 0){
          float v = acc + other + bmp[col0 + o2];
          if (msel == 3) v = sigm(v);
          astoref(projbuf + (size_t)b*1024 + msel*256 + col0 + o2, v);
        }
      }
      arrive1(arrv + F_K(wg), (uint)(t+1));
      {  // gp(t+1) = G_emb[t+1] + W_hh·h_t
        float a0 = G_emb[(size_t)((t+1)*BQ + p1_b)*2048 + pcol];
        float a1 = 0.f, a2 = 0.f, a3 = 0.f;
        const float4* wh = (const float4*)(W_hh + (size_t)rrow*HID);
        const float4* xv = (const float4*)(hs + p1_b*516);
        #pragma unroll 2
        for (int k = 0; k < 128; k += 4){
          float4 w, x;
          w=wh[k+0]; x=xv[k+0]; a0=fmaf(w.x,x.x,a0); a0=fmaf(w.y,x.y,a0); a0=fmaf(w.z,x.z,a0); a0=fmaf(w.w,x.w,a0);
          w=wh[k+1]; x=xv[k+1]; a1=fmaf(w.x,x.x,a1); a1=fmaf(w.y,x.y,a1); a1=fmaf(w.z,x.z,a1); a1=fmaf(w.w,x.w,a1);
          w=wh[k+2]; x=xv[k+2]; a2=fmaf(w.x,x.x,a2); a2=fmaf(w.y,x.y,a2); a2=fmaf(w.z,x.z,a2); a2=fmaf(w.w,x.w,a2);
          w=wh[k+3]; x=xv[k+3]; a3=fmaf(w.x,x.x,a3); a3=fmaf(w.y,x.y,a3); a3=fmaf(w.z,x.z,a3); a3=fmaf(w.w,x.w,a3);
        }
        astoref(gp_g + (size_t)p1_b*2048 + pcol, (a0+a1)+(a2+a3));
      }
      arrive1(arrv + F_G(wg), (uint)(t+1));
    }
  } else if (wg < NB_REC){
    // =================== BATCH role ===================
    const int b = wg - NB_PROJ;
    float* keyT  = smem;                    // [64][8]
    float* wv_s  = smem + 512;              // 256 (+ er_s 256 contiguous)
    float* er_s  = smem + 768;
    float* rv_s  = smem + 1024;             // 64
    float* rvp   = smem + 1088;             // 1024
    float* wgt   = smem + 2112;             // 64
    int*   slotl = (int*)(smem + 2176);     // 64
    int*   ge_s  = (int*)(smem + 2240);     // 32
    float* knrm  = smem + 2272;             // 8
    u64*   cnd   = (u64*)(smem + 2280);     // 8*4*8 u64
    float* mrow = mem_row + (size_t)b*NSLOT*MD;
    float* mT   = memT    + (size_t)b*MD*NSLOT;

    // prologue: init memory + h_0
    {
      float4 iv = make_float4(1e-6f,1e-6f,1e-6f,1e-6f);
      for (int i = tid; i < NSLOT*MD/4; i += 256){
        *(float4*)(mrow + (size_t)i*4) = iv;
        *(float4*)(mT   + (size_t)i*4) = iv;
      }
    }
    float c0 = 0.f, c1 = 0.f;
    {
      float4 gA = *(const float4*)(G_emb + (size_t)b*2048 + tid*8);
      float4 gB = *(const float4*)(G_emb + (size_t)b*2048 + tid*8 + 4);
      c0 = sigm(gA.x)*tanhf(gA.z);
      float h0v = sigm(gA.w)*tanhf(c0);
      c1 = sigm(gB.x)*tanhf(gB.z);
      float h1v = sigm(gB.w)*tanhf(c1);
      astoref(H_all + (size_t)b*HID + tid*2,     h0v);
      astoref(H_all + (size_t)b*HID + tid*2 + 1, h1v);
    }
    asm volatile("s_waitcnt vmcnt(0)" ::: "memory");
    __syncthreads();
    if (tid == 0) astoreu32(arrv + F_H(b), 1u);

    const int lane = tid & 63, wv_id = tid >> 6;
    #pragma clang loop unroll(disable)
    for (int t = 0; t < T_STEPS-1; ++t){
      // ---- wait keys; stage projbuf[b] ----
      if (tid < 128) poll1(arrv + F_K(tid), (uint)(t+1));
      __syncthreads();
      {
        float4 v; AL4(v, (const float4*)(projbuf + (size_t)b*1024) + tid); AWAIT();
        if (tid < 128){
          int q = tid*4;
          keyT[((q+0)&63)*8 + ((q+0)>>6)] = v.x;
          keyT[((q+1)&63)*8 + ((q+1)>>6)] = v.y;
          keyT[((q+2)&63)*8 + ((q+2)>>6)] = v.z;
          keyT[((q+3)&63)*8 + ((q+3)>>6)] = v.w;
        } else {
          *(float4*)(wv_s + (tid-128)*4) = v;    // wv then er (contiguous)
        }
      }
      __syncthreads();
      if (tid < 8){
        float kn = 0.f;
        #pragma unroll 8
        for (int d = 0; d < 64; ++d){ float kv = keyT[d*8 + tid]; kn = fmaf(kv,kv,kn); }
        knrm[tid] = 1.f / (sqrtf(kn) + EPSN);
      }
      // ---- scores: 4 slots/thread x 8 keys ----
      float ss0=0,ss1=0,ss2=0,ss3=0;
      float sc[8][4] = {};
      {
        const float* mp = mT + tid;
        #pragma unroll 2
        for (int d = 0; d < 64; ++d){
          float4 ka = *(const float4*)(keyT + d*8);
          float4 kb = *(const float4*)(keyT + d*8 + 4);
          float m0 = mp[d*1024], m1 = mp[d*1024+256], m2 = mp[d*1024+512], m3 = mp[d*1024+768];
          ss0=fmaf(m0,m0,ss0); ss1=fmaf(m1,m1,ss1); ss2=fmaf(m2,m2,ss2); ss3=fmaf(m3,m3,ss3);
          sc[0][0]=fmaf(m0,ka.x,sc[0][0]); sc[0][1]=fmaf(m1,ka.x,sc[0][1]); sc[0][2]=fmaf(m2,ka.x,sc[0][2]); sc[0][3]=fmaf(m3,ka.x,sc[0][3]);
          sc[1][0]=fmaf(m0,ka.y,sc[1][0]); sc[1][1]=fmaf(m1,ka.y,sc[1][1]); sc[1][2]=fmaf(m2,ka.y,sc[1][2]); sc[1][3]=fmaf(m3,ka.y,sc[1][3]);
          sc[2][0]=fmaf(m0,ka.z,sc[2][0]); sc[2][1]=fmaf(m1,ka.z,sc[2][1]); sc[2][2]=fmaf(m2,ka.z,sc[2][2]); sc[2][3]=fmaf(m3,ka.z,sc[2][3]);
          sc[3][0]=fmaf(m0,ka.w,sc[3][0]); sc[3][1]=fmaf(m1,ka.w,sc[3][1]); sc[3][2]=fmaf(m2,ka.w,sc[3][2]); sc[3][3]=fmaf(m3,ka.w,sc[3][3]);
          sc[4][0]=fmaf(m0,kb.x,sc[4][0]); sc[4][1]=fmaf(m1,kb.x,sc[4][1]); sc[4][2]=fmaf(m2,kb.x,sc[4][2]); sc[4][3]=fmaf(m3,kb.x,sc[4][3]);
          sc[5][0]=fmaf(m0,kb.y,sc[5][0]); sc[5][1]=fmaf(m1,kb.y,sc[5][1]); sc[5][2]=fmaf(m2,kb.y,sc[5][2]); sc[5][3]=fmaf(m3,kb.y,sc[5][3]);
          sc[6][0]=fmaf(m0,kb.z,sc[6][0]); sc[6][1]=fmaf(m1,kb.z,sc[6][1]); sc[6][2]=fmaf(m2,kb.z,sc[6][2]); sc[6][3]=fmaf(m3,kb.z,sc[6][3]);
          sc[7][0]=fmaf(m0,kb.w,sc[7][0]); sc[7][1]=fmaf(m1,kb.w,sc[7][1]); sc[7][2]=fmaf(m2,kb.w,sc[7][2]); sc[7][3]=fmaf(m3,kb.w,sc[7][3]);
        }
      }
      float rn0 = BETA/(sqrtf(ss0)+EPSN), rn1 = BETA/(sqrtf(ss1)+EPSN);
      float rn2 = BETA/(sqrtf(ss2)+EPSN), rn3 = BETA/(sqrtf(ss3)+EPSN);
      // ---- per-wave top8 per key (registers only) ----
      #pragma unroll
      for (int key = 0; key < 8; ++key){
        u64 p0 = packsc(sc[key][0]*rn0, tid);
        u64 p1 = packsc(sc[key][1]*rn1, tid+256);
        u64 p2 = packsc(sc[key][2]*rn2, tid+512);
        u64 p3 = packsc(sc[key][3]*rn3, tid+768);
        #pragma unroll
        for (int r = 0; r < 8; ++r){
          u64 m01 = p0 > p1 ? p0 : p1;
          u64 m23 = p2 > p3 ? p2 : p3;
          u64 m = m01 > m23 ? m01 : m23;
          #pragma unroll
          for (int o = 32; o; o >>= 1){ u64 q = __shfl_xor(m, o); if (q > m) m = q; }
          if (p0 == m) p0 = 0; else if (p1 == m) p1 = 0;
          else if (p2 == m) p2 = 0; else if (p3 == m) p3 = 0;
          if (lane == 0) cnd[(key*4 + wv_id)*8 + r] = m;
        }
      }
      __syncthreads();
      // ---- merge 4 sorted lists + softmax (8 threads) ----
      if (tid < 8){
        const u64* cl = cnd + tid*32;
        int i0=0,i1=0,i2=0,i3=0;
        float vals[8]; int sl[8];
        #pragma unroll
        for (int r = 0; r < 8; ++r){
          u64 a = cl[i0], bb2 = cl[8+i1], c = cl[16+i2], d = cl[24+i3];
          u64 m1_ = a > bb2 ? a : bb2;
          u64 m2_ = c > d ? c : d;
          u64 m = m1_ > m2_ ? m1_ : m2_;
          if (m == a) ++i0; else if (m == bb2) ++i1; else if (m == c) ++i2; else ++i3;
          vals[r] = unpackval(m) * knrm[tid];
          sl[r]   = unpackslot(m);
        }
        float vm = vals[0], et[8], sum = 0.f;
        #pragma unroll
        for (int r = 0; r < 8; ++r){ et[r] = expf(vals[r]-vm); sum += et[r]; }
        float rs = 1.f/sum;
        #pragma unroll
        for (int r = 0; r < 8; ++r){ wgt[tid*8+r] = et[r]*rs; slotl[tid*8+r] = sl[r]; }
      }
      __syncthreads();
      // ---- rv partials (pre-write) + write-dedup map ----
      #pragma unroll
      for (int jj = 0; jj < 4; ++jj){
        int it = tid + 256*jj;
        int hh = it >> 8, rr = (it >> 6) & 3, d = it & 63;
        float w0 = wgt[hh*8+rr],   w1 = wgt[hh*8+rr+4];
        int   s0 = slotl[hh*8+rr], s1 = slotl[hh*8+rr+4];
        rvp[it] = w0*mrow[(size_t)s0*64+d] + w1*mrow[(size_t)s1*64+d];
      }
      if (tid < 32){
        int me = slotl[32+tid], g = tid;
        for (int e = 0; e < 32; ++e){ if (e < tid && slotl[32+e] == me){ g = e; break; } }
        ge_s[tid] = g;
      }
      __syncthreads();
      // rv finalize
      if (tid < 64){
        float s = 0.f;
        #pragma unroll
        for (int i = 0; i < 16; ++i) s += rvp[i*64 + tid];
        rv_s[tid] = 0.25f*s;
      }
      // erase+add (closed form per unique slot)
      #pragma unroll
      for (int jj = 0; jj < 8; ++jj){
        int it = tid + 256*jj;          // (g,d)
        int g = it >> 6, d = it & 63;
        if (ge_s[g] == g){
          float keep = 1.f, add = 0.f;
          for (int e = 0; e < 32; ++e){
            if (ge_s[e] == g){
              float w = wgt[32+e]; int h = e >> 3;
              keep *= (1.f - w*er_s[h*64+d]);
              add  += w*wv_s[h*64+d];
            }
          }
          int slot = slotl[32+g];
          float nv = mrow[(size_t)slot*64+d]*keep + add;
          mrow[(size_t)slot*64+d] = nv;
          mT[(size_t)d*1024+slot] = nv;
        }
      }
      __syncthreads();
      // ---- gates = gp + WT·rv ; LSTM ; publish h_{t+1} ----
      if (tid < 128) poll1(arrv + F_G(tid), (uint)(t+1));
      __syncthreads();
      float ga0,ga1,ga2,ga3,ga4,ga5,ga6,ga7;
      {
        float4 g0, g1;
        AL4(g0, (const float4*)(gp_g + (size_t)b*2048 + tid*8));
        AL4(g1, (const float4*)(gp_g + (size_t)b*2048 + tid*8 + 4));
        AWAIT();
        ga0=g0.x; ga1=g0.y; ga2=g0.z; ga3=g0.w; ga4=g1.x; ga5=g1.y; ga6=g1.z; ga7=g1.w;
      }
      {
        const float4* wt = (const float4*)(WT + tid*8);
        #pragma unroll 4
        for (int d = 0; d < 64; ++d){
          float r = rv_s[d];
          float4 w0 = wt[d*512], w1 = wt[d*512 + 1];
          ga0=fmaf(r,w0.x,ga0); ga1=fmaf(r,w0.y,ga1); ga2=fmaf(r,w0.z,ga2); ga3=fmaf(r,w0.w,ga3);
          ga4=fmaf(r,w1.x,ga4); ga5=fmaf(r,w1.y,ga5); ga6=fmaf(r,w1.z,ga6); ga7=fmaf(r,w1.w,ga7);
        }
      }
      c0 = sigm(ga1)*c0 + sigm(ga0)*tanhf(ga2);
      float h0v = sigm(ga3)*tanhf(c0);
      c1 = sigm(ga5)*c1 + sigm(ga4)*tanhf(ga6);
      float h1v = sigm(ga7)*tanhf(c1);
      astoref(H_all + (size_t)((t+1)*BQ + b)*HID + tid*2,     h0v);
      astoref(H_all + (size_t)((t+1)*BQ + b)*HID + tid*2 + 1, h1v);
      asm volatile("s_waitcnt vmcnt(0)" ::: "memory");
      __syncthreads();
      if (tid == 0) astoreu32(arrv + F_H(b), (uint)(t+2));
    }
  }
}

// ---------------- phase B: logits = H_all[2048,512] @ W_out[512,32000] + b_out ----------------
__global__ __launch_bounds__(256) void gemm_out(const float* __restrict__ A,
                                                const float* __restrict__ Bmat,
                                                const float* __restrict__ bias,
                                                float* __restrict__ C){
  __shared__ __align__(16) float As[16*132];
  __shared__ __align__(16) float Bs[16*64];
  int mt = blockIdx.x & 15, nt = blockIdx.x >> 4;
  int m0 = mt*128, n0 = nt*64;
  int tx = threadIdx.x & 15, ty = threadIdx.x >> 4;
  float acc[8][4] = {};
  for (int k0 = 0; k0 < 512; k0 += 16){
    int mm = threadIdx.x >> 1, kq = (threadIdx.x & 1)*8;
    float4 a0 = *(const float4*)(A + (size_t)(m0+mm)*512 + k0 + kq);
    float4 a1 = *(const float4*)(A + (size_t)(m0+mm)*512 + k0 + kq + 4);
    As[(kq+0)*132+mm]=a0.x; As[(kq+1)*132+mm]=a0.y; As[(kq+2)*132+mm]=a0.z; As[(kq+3)*132+mm]=a0.w;
    As[(kq+4)*132+mm]=a1.x; As[(kq+5)*132+mm]=a1.y; As[(kq+6)*132+mm]=a1.z; As[(kq+7)*132+mm]=a1.w;
    int kk2 = threadIdx.x >> 4, nq = (threadIdx.x & 15)*4;
    *(float4*)(Bs + kk2*64 + nq) = *(const float4*)(Bmat + (size_t)(k0+kk2)*VOCAB + n0 + nq);
    __syncthreads();
    #pragma unroll
    for (int kk = 0; kk < 16; ++kk){
      float4 x0 = *(const float4*)(As + kk*132 + ty*8);
      float4 x1 = *(const float4*)(As + kk*132 + ty*8 + 4);
      float4 bv = *(const float4*)(Bs + kk*64 + tx*4);
      float aa[8] = {x0.x,x0.y,x0.z,x0.w,x1.x,x1.y,x1.z,x1.w};
      float bb[4] = {bv.x,bv.y,bv.z,bv.w};
      #pragma unroll
      for (int i = 0; i < 8; ++i)
        #pragma unroll
        for (int j = 0; j < 4; ++j)
          acc[i][j] = fmaf(aa[i], bb[j], acc[i][j]);
    }
    __syncthreads();
  }
  #pragma unroll
  for (int i = 0; i < 8; ++i){
    int m = m0 + ty*8 + i;
    int bq = m & 15, tt = m >> 4;
    float* crow = C + ((size_t)bq*T_STEPS + tt)*VOCAB + n0 + tx*4;
    #pragma unroll
    for (int j = 0; j < 4; ++j) crow[j] = acc[i][j] + bias[n0 + tx*4 + j];
  }
}

extern "C" void kernel_launch(void* const* d_in, const int* in_sizes, int n_in,
                              void* d_out, int out_size, void* d_ws, size_t ws_size,
                              hipStream_t stream){
  const int*   seq   = (const int*)d_in[0];
  const float* E     = (const float*)d_in[1];
  const float* W_ih  = (const float*)d_in[2];
  const float* W_hh  = (const float*)d_in[3];
  const float* b_ih  = (const float*)d_in[4];
  const float* b_hh  = (const float*)d_in[5];
  const float* W_out = (const float*)d_in[6];
  const float* b_out = (const float*)d_in[7];
  const float* W_rk  = (const float*)d_in[8];
  const float* b_rk  = (const float*)d_in[9];
  const float* W_wk  = (const float*)d_in[10];
  const float* b_wk  = (const float*)d_in[11];
  const float* W_wv  = (const float*)d_in[12];
  const float* b_wv  = (const float*)d_in[13];
  const float* W_er  = (const float*)d_in[14];
  const float* b_er  = (const float*)d_in[15];
  float* out = (float*)d_out;
  (void)in_sizes; (void)n_in; (void)out_size; (void)ws_size;

  char* ws = (char*)d_ws;
  size_t off = 0;
  auto alloc = [&](size_t bytes) -> void* {
    off = (off + 255) & ~(size_t)255;
    void* p = ws + off;
    off += bytes;
    return p;
  };
  float* EMB     = (float*)alloc((size_t)2048*256*4);
  float* G_emb   = (float*)alloc((size_t)2048*2048*4);
  float* H_all   = (float*)alloc((size_t)2048*512*4);
  float* mem_row = (float*)alloc((size_t)16*1024*64*4);
  float* memT    = (float*)alloc((size_t)16*64*1024*4);
  float* projbuf = (float*)alloc((size_t)16*1024*4);
  float* gp_g    = (float*)alloc((size_t)16*2048*4);
  float* WT      = (float*)alloc((size_t)64*2048*4);
  uint*  arrv    = (uint*)alloc((size_t)NFLAGS*32*4);

  hipMemsetAsync(arrv, 0, (size_t)NFLAGS*32*4, stream);
  prep_emb<<<2048, 256, 0, stream>>>(E, seq, EMB);
  gemm_emb<<<1024, 256, 0, stream>>>(EMB, W_ih, b_ih, b_hh, G_emb);
  make_wrvT<<<512, 256, 0, stream>>>(W_ih, WT);
  recur_kernel<<<NB_REC, 256, 0, stream>>>(
      W_hh, WT, W_rk, b_rk, W_wk, b_wk, W_wv, b_wv, W_er, b_er,
      G_emb, H_all, mem_row, memT, projbuf, gp_g, arrv);
  gemm_out<<<16*500, 256, 0, stream>>>(H_all, W_out, b_out, out);
}

// Round 10
// 7005.804 us; speedup vs baseline: 1.1824x; 1.1824x over previous
//
#include <hip/hip_runtime.h>
#include <hip/hip_bf16.h>
#include <stdint.h>

typedef unsigned int uint;
typedef unsigned long long u64;

#define T_STEPS 128
#define BQ 16
#define HID 512
#define NSLOT 1024
#define MD 64
#define VOCAB 32000
#define BETA 1.000001f
#define EPSN 1e-8f

#define NWK 128          // worker WGs (proj+slot+gate roles)
#define NBT 16           // batch WGs (merge+rv+LSTM)

// flag lines (128B apart), monotonic generations, memset-0 per launch
#define LF_FH(b)  ((b)*32)            // 0..15   h(t) ready (gen t+1); batch -> workers
#define LF_FP(w)  ((16+(w))*32)       // 16..47  proj WG w published keys+ew for t (gen t+1)
#define LF_FC(w)  ((48+(w))*32)       // 48..175 slot WG w cand for t (gen t+1)
#define LF_FRV(b) ((176+(b))*32)      // 176..191 rv+wlist for t (gen t+1)
#define LF_FG(w)  ((192+(w))*32)      // 192..319 gates(t) from gate WG w (gen t+1)
#define NLINES    320

// agent-coherent (bypass L1/L2); batched waitcnt (+sched_barrier, rule #18)
#define AL4(dst, p) asm volatile("global_load_dwordx4 %0, %1, off sc0 sc1" : "=v"(dst) : "v"(p))
#define ALF(dst, p) asm volatile("global_load_dword %0, %1, off sc0 sc1" : "=v"(dst) : "v"(p))
#define AWAIT() do { asm volatile("s_waitcnt vmcnt(0)" ::: "memory"); __builtin_amdgcn_sched_barrier(0); } while(0)
#define DRAIN() asm volatile("s_waitcnt vmcnt(0)" ::: "memory")

__device__ __forceinline__ float sigm(float x){ return 1.f/(1.f+expf(-x)); }
__device__ __forceinline__ void astoref(float* p, float v){
  __hip_atomic_store(p, v, __ATOMIC_RELAXED, __HIP_MEMORY_SCOPE_AGENT);
}
__device__ __forceinline__ void astoreu32(uint* p, uint v){
  __hip_atomic_store(p, v, __ATOMIC_RELAXED, __HIP_MEMORY_SCOPE_AGENT);
}
__device__ __forceinline__ void astoreu64(u64* p, u64 v){
  __hip_atomic_store(p, v, __ATOMIC_RELAXED, __HIP_MEMORY_SCOPE_AGENT);
}
__device__ __forceinline__ u64 aloadu64(const u64* p){
  return __hip_atomic_load((u64*)p, __ATOMIC_RELAXED, __HIP_MEMORY_SCOPE_AGENT);
}
__device__ __forceinline__ uint aloadu32(const uint* p){
  return __hip_atomic_load((uint*)p, __ATOMIC_RELAXED, __HIP_MEMORY_SCOPE_AGENT);
}
__device__ __forceinline__ void poll1(const uint* p, uint gen){
  while (aloadu32(p) < gen) __builtin_amdgcn_s_sleep(2);
}

// pack (score, slot): u64 max == (max value, min slot on ties) — matches lax.top_k
__device__ __forceinline__ u64 packsc(float v, int slot){
  uint u = __float_as_uint(v);
  u = (u & 0x80000000u) ? ~u : (u | 0x80000000u);
  return ((u64)u << 10) | (u64)(1023 - slot);
}
__device__ __forceinline__ float unpackval(u64 p){
  uint u = (uint)(p >> 10);
  uint bits = (u & 0x80000000u) ? (u & 0x7fffffffu) : ~u;
  return __uint_as_float(bits);
}
__device__ __forceinline__ int unpackslot(u64 p){ return 1023 - (int)(p & 1023u); }

// LDS float offsets (worker); batch uses low region as scratch
#define L_MEM  0        // mem_s[128][68]
#define L_NRM  8704     // nrm_s[128]
#define L_HS   8832     // hs[16][516]
#define L_KEY  17088    // key_s[512]
#define L_KNRM 17600    // knrm_s[8]
#define L_SC   17608    // sc_s[8][128]
#define L_WV   18632    // wv_s[256]
#define L_ER   18888    // er_s[256]
#define L_WL   19144    // wl_s[32] u64 (64 f, 8B-aligned: 19144*4=76576)
#define L_RVS  19208    // rv_s[16][64]
#define L_WTS  20232    // WT_s[64][16]
#define L_TOT  21256    // 85,024 B

// ---------------- pre-kernels ----------------
__global__ __launch_bounds__(256) void prep_emb(const float* __restrict__ E,
                                                const int* __restrict__ seq,
                                                float* __restrict__ EMB){
  int m = blockIdx.x, t = m >> 4, b = m & 15;
  int x = seq[b*T_STEPS + t];
  EMB[(size_t)m*256 + threadIdx.x] = E[(size_t)x*256 + threadIdx.x];
}

// G_emb[m][p] packed p=u*4+g, r=g*512+u
__global__ __launch_bounds__(256) void gemm_emb(const float* __restrict__ A,
                                                const float* __restrict__ W_ih,
                                                const float* __restrict__ b_ih,
                                                const float* __restrict__ b_hh,
                                                float* __restrict__ C){
  __shared__ __align__(16) float As[16*68];
  __shared__ __align__(16) float Bs[16*68];
  int mt = blockIdx.x & 31, nt = blockIdx.x >> 5;
  int m0 = mt*64, n0 = nt*64;
  int tx = threadIdx.x & 15, ty = threadIdx.x >> 4;
  float acc[4][4] = {};
  for (int k0 = 0; k0 < 256; k0 += 16){
    int mm = threadIdx.x >> 2, kq = (threadIdx.x & 3)*4;
    float4 a = *(const float4*)(A + (size_t)(m0+mm)*256 + k0 + kq);
    As[(kq+0)*68+mm]=a.x; As[(kq+1)*68+mm]=a.y; As[(kq+2)*68+mm]=a.z; As[(kq+3)*68+mm]=a.w;
    int pp = n0 + mm;
    int r = (pp & 3)*512 + (pp >> 2);
    float4 bv = *(const float4*)(W_ih + (size_t)r*320 + k0 + kq);
    Bs[(kq+0)*68+mm]=bv.x; Bs[(kq+1)*68+mm]=bv.y; Bs[(kq+2)*68+mm]=bv.z; Bs[(kq+3)*68+mm]=bv.w;
    __syncthreads();
    #pragma unroll
    for (int kk = 0; kk < 16; ++kk){
      float4 av = *(const float4*)(As + kk*68 + ty*4);
      float4 bb = *(const float4*)(Bs + kk*68 + tx*4);
      float aa[4] = {av.x,av.y,av.z,av.w};
      float bv2[4] = {bb.x,bb.y,bb.z,bb.w};
      #pragma unroll
      for (int i = 0; i < 4; ++i)
        #pragma unroll
        for (int j = 0; j < 4; ++j)
          acc[i][j] = fmaf(aa[i], bv2[j], acc[i][j]);
    }
    __syncthreads();
  }
  #pragma unroll
  for (int i = 0; i < 4; ++i){
    int m = m0 + ty*4 + i;
    #pragma unroll
    for (int j = 0; j < 4; ++j){
      int pp = n0 + tx*4 + j;
      int r = (pp & 3)*512 + (pp >> 2);
      C[(size_t)m*2048 + pp] = acc[i][j] + b_ih[r] + b_hh[r];
    }
  }
}

// WT[k][p] = W_ih[r(p)][256+k]  (packed-p rv-weight transpose)
__global__ __launch_bounds__(256) void make_wrvT(const float* __restrict__ W_ih,
                                                 float* __restrict__ WT){
  int idx = blockIdx.x*256 + threadIdx.x;
  int k = idx >> 11, p = idx & 2047;
  int r = (p & 3)*512 + (p >> 2);
  WT[idx] = W_ih[(size_t)r*320 + 256 + k];
}

// ---------------- R10: distributed compute + per-need direct flags ----------------
// blocks [0,128): workers (proj[<32] + slot + gate); [128,144): batch WGs
__global__ __launch_bounds__(256) void recur_kernel(
    const float* __restrict__ W_hh, const float* __restrict__ WT,
    const float* __restrict__ W_rk, const float* __restrict__ b_rk,
    const float* __restrict__ W_wk, const float* __restrict__ b_wk,
    const float* __restrict__ W_wv, const float* __restrict__ b_wv,
    const float* __restrict__ W_er, const float* __restrict__ b_er,
    const float* __restrict__ G_emb, float* __restrict__ H_all,
    float* __restrict__ H_pub, float* __restrict__ mem_g,
    float* __restrict__ projpub, float* __restrict__ gatespub,
    float* __restrict__ rvpub, u64* __restrict__ cand,
    u64* __restrict__ wlist, uint* __restrict__ arrv)
{
  __shared__ __align__(16) float smem[L_TOT];
  const int tid = threadIdx.x;
  const int wg  = blockIdx.x;

  if (wg < NWK){
    // =================== WORKER ===================
    float* mem_s  = smem + L_MEM;
    float* nrm_s  = smem + L_NRM;
    float* hs     = smem + L_HS;
    float* key_s  = smem + L_KEY;
    float* knrm_s = smem + L_KNRM;
    float* sc_s   = smem + L_SC;
    float* wv_s   = smem + L_WV;
    float* er_s   = smem + L_ER;
    u64*   wl_s   = (u64*)(smem + L_WL);
    float* rv_s   = smem + L_RVS;
    float* WT_s   = smem + L_WTS;

    const int b_s = wg >> 3, rg = wg & 7, s0 = rg*128;   // slot role
    const int gb = tid >> 4, gc = tid & 15;              // gate role thread map
    const int pcol = wg*16 + gc;
    const int rrow = (pcol & 3)*512 + (pcol >> 2);
    float* mslice_g = mem_g + ((size_t)b_s*NSLOT + s0)*MD;
    // proj role constants (wg<32): key col c1 = wg*16+j, ew col c2 = 512+wg*16+j
    const float* W1 = (wg < 16) ? W_rk : W_wk;
    const float* B1 = (wg < 16) ? b_rk : b_wk;
    const float* W2 = (wg < 16) ? W_wv : W_er;
    const float* B2 = (wg < 16) ? b_wv : b_er;
    const int cc = (wg & 15)*16 + gc;                    // col within 256-matrix
    const float pb1 = (wg < 32) ? B1[cc] : 0.f;
    const float pb2 = (wg < 32) ? B2[cc] : 0.f;

    // prologue: WT slice -> LDS; mem slice init + mirror; norms
    for (int i = tid; i < 64*16; i += 256){
      int d = i >> 4, c = i & 15;
      WT_s[i] = WT[(size_t)d*2048 + wg*16 + c];
    }
    for (int i = tid; i < 128*MD; i += 256){
      mem_s[(i >> 6)*68 + (i & 63)] = 1e-6f;
      astoref(mslice_g + i, 1e-6f);
    }
    __syncthreads();
    {
      int s = tid >> 1, half = tid & 1;
      const float4* mp = (const float4*)(mem_s + s*68 + half*32);
      float sum = 0.f;
      #pragma unroll
      for (int q = 0; q < 8; ++q){
        float4 v = mp[q];
        sum = fmaf(v.x,v.x,sum); sum = fmaf(v.y,v.y,sum);
        sum = fmaf(v.z,v.z,sum); sum = fmaf(v.w,v.w,sum);
      }
      sum += __shfl_xor(sum, 1);
      if (half == 0) nrm_s[s] = sqrtf(sum) + EPSN;
    }
    __syncthreads();

    #pragma clang loop unroll(disable)
    for (int t = 0; t < T_STEPS-1; ++t){
      const int par = t & 1, parp = par ^ 1;
      // ---- memory update for step t-1 writes (inputs all visible since t-1) ----
      if (t > 0){
        if (tid < 32) wl_s[tid] = aloadu64(wlist + (size_t)b_s*32 + tid);
        if (tid < 64){
          float4 v; AL4(v, (const float4*)(projpub + (size_t)parp*BQ*1024 + (size_t)b_s*1024 + 512) + tid);
          AWAIT();
          *(float4*)(wv_s + tid*4) = v;
        } else if (tid < 128){
          int i = tid - 64;
          float4 v; AL4(v, (const float4*)(projpub + (size_t)parp*BQ*1024 + (size_t)b_s*1024 + 768) + i);
          AWAIT();
          *(float4*)(er_s + i*4) = v;
        }
        __syncthreads();
        if (tid < 64){
          const int d = tid;
          #pragma unroll 1
          for (int e = 0; e < 32; ++e){        // erases (keep = prod over heads)
            u64 w64 = wl_s[e];
            int sl = (int)(w64 & 0xffffffffu);
            if (sl >= s0 && sl < s0+128){
              float w = __uint_as_float((uint)(w64 >> 32));
              mem_s[(sl-s0)*68 + d] *= (1.f - w*er_s[(e >> 3)*64 + d]);
            }
          }
          #pragma unroll 1
          for (int e = 0; e < 32; ++e){        // adds
            u64 w64 = wl_s[e];
            int sl = (int)(w64 & 0xffffffffu);
            if (sl >= s0 && sl < s0+128){
              float w = __uint_as_float((uint)(w64 >> 32));
              mem_s[(sl-s0)*68 + d] += w*wv_s[(e >> 3)*64 + d];
            }
          }
          #pragma unroll 1
          for (int e = 0; e < 32; ++e){        // mirror changed rows
            u64 w64 = wl_s[e];
            int sl = (int)(w64 & 0xffffffffu);
            if (sl >= s0 && sl < s0+128)
              astoref(mslice_g + (sl-s0)*MD + d, mem_s[(sl-s0)*68 + d]);
          }
        }
        __syncthreads();
        {
          int s = tid >> 1, half = tid & 1;
          const float4* mp = (const float4*)(mem_s + s*68 + half*32);
          float sum = 0.f;
          #pragma unroll
          for (int q = 0; q < 8; ++q){
            float4 v = mp[q];
            sum = fmaf(v.x,v.x,sum); sum = fmaf(v.y,v.y,sum);
            sum = fmaf(v.z,v.z,sum); sum = fmaf(v.w,v.w,sum);
          }
          sum += __shfl_xor(sum, 1);
          if (half == 0) nrm_s[s] = sqrtf(sum) + EPSN;
        }
      }
      // ---- wait h(t) (16 producers) + stage all 16 batches ----
      if (tid < 16) poll1(arrv + LF_FH(tid), (uint)(t+1));
      __syncthreads();
      {
        float4 v0,v1,v2,v3,v4,v5,v6,v7;
        const float4* hp = (const float4*)H_pub;
        AL4(v0, hp + tid);        AL4(v1, hp + tid + 256);
        AL4(v2, hp + tid + 512);  AL4(v3, hp + tid + 768);
        AL4(v4, hp + tid + 1024); AL4(v5, hp + tid + 1280);
        AL4(v6, hp + tid + 1536); AL4(v7, hp + tid + 1792);
        AWAIT();
        int i;
        i = tid;        *(float4*)(hs + (i>>7)*516 + (i&127)*4) = v0;
        i = tid + 256;  *(float4*)(hs + (i>>7)*516 + (i&127)*4) = v1;
        i = tid + 512;  *(float4*)(hs + (i>>7)*516 + (i&127)*4) = v2;
        i = tid + 768;  *(float4*)(hs + (i>>7)*516 + (i&127)*4) = v3;
        i = tid + 1024; *(float4*)(hs + (i>>7)*516 + (i&127)*4) = v4;
        i = tid + 1280; *(float4*)(hs + (i>>7)*516 + (i&127)*4) = v5;
        i = tid + 1536; *(float4*)(hs + (i>>7)*516 + (i&127)*4) = v6;
        i = tid + 1792; *(float4*)(hs + (i>>7)*516 + (i&127)*4) = v7;
      }
      __syncthreads();
      // ---- proj (wg<32): thread = (batch gb, col-offset gc); two 512-deep dots ----
      if (wg < 32){
        float a0=0.f,a1=0.f,b0=0.f,b1=0.f;
        const float* hp = hs + gb*516;
        const float* w1 = W1 + cc;
        const float* w2 = W2 + cc;
        #pragma unroll 4
        for (int k = 0; k < 512; k += 2){
          float h0 = hp[k], h1 = hp[k+1];
          a0 = fmaf(h0, w1[(size_t)k*256], a0);
          b0 = fmaf(h0, w2[(size_t)k*256], b0);
          a1 = fmaf(h1, w1[(size_t)(k+1)*256], a1);
          b1 = fmaf(h1, w2[(size_t)(k+1)*256], b1);
        }
        float v1 = a0 + a1 + pb1;
        float v2 = b0 + b1 + pb2;
        if (wg >= 16) v2 = sigm(v2);   // er cols get sigmoid
        astoref(projpub + (size_t)par*BQ*1024 + (size_t)gb*1024 + wg*16 + gc, v1);
        astoref(projpub + (size_t)par*BQ*1024 + (size_t)gb*1024 + 512 + wg*16 + gc, v2);
      }
      DRAIN();
      __syncthreads();
      if (wg < 32 && tid == 0) astoreu32(arrv + LF_FP(wg), (uint)(t+1));
      // ---- wait keys (32 producers), stage keys of my batch ----
      if (tid < 32) poll1(arrv + LF_FP(tid), (uint)(t+1));
      __syncthreads();
      if (tid < 128){
        float4 kv; AL4(kv, (const float4*)(projpub + (size_t)par*BQ*1024 + (size_t)b_s*1024) + tid);
        AWAIT();
        *(float4*)(key_s + tid*4) = kv;
      }
      __syncthreads();
      if (tid < 8){
        const float4* kp = (const float4*)(key_s + tid*MD);
        float sum = 0.f;
        #pragma unroll
        for (int q = 0; q < 16; ++q){
          float4 v = kp[q];
          sum = fmaf(v.x,v.x,sum); sum = fmaf(v.y,v.y,sum);
          sum = fmaf(v.z,v.z,sum); sum = fmaf(v.w,v.w,sum);
        }
        knrm_s[tid] = sqrtf(sum) + EPSN;
      }
      __syncthreads();
      // ---- scores + local top8 (R4-proven) ----
      {
        int s = tid >> 1, kh = tid & 1;
        const float4* mp = (const float4*)(mem_s + s*68);
        float rnm = 1.f / nrm_s[s];
        float acc4[4] = {0.f,0.f,0.f,0.f};
        #pragma unroll
        for (int q = 0; q < 16; ++q){
          float4 m = mp[q];
          #pragma unroll
          for (int kk = 0; kk < 4; ++kk){
            float4 k4 = *(const float4*)(key_s + (kh*4+kk)*MD + q*4);
            acc4[kk] = fmaf(m.x,k4.x,acc4[kk]); acc4[kk] = fmaf(m.y,k4.y,acc4[kk]);
            acc4[kk] = fmaf(m.z,k4.z,acc4[kk]); acc4[kk] = fmaf(m.w,k4.w,acc4[kk]);
          }
        }
        #pragma unroll
        for (int kk = 0; kk < 4; ++kk){
          int key = kh*4 + kk;
          sc_s[key*128 + s] = BETA * acc4[kk] * rnm / knrm_s[key];
        }
      }
      __syncthreads();
      {
        int wid = tid >> 6, lane = tid & 63;
        #pragma unroll
        for (int kk = 0; kk < 2; ++kk){
          int key = wid*2 + kk;
          u64 p0 = packsc(sc_s[key*128 + lane],      s0 + lane);
          u64 p1 = packsc(sc_s[key*128 + 64 + lane], s0 + 64 + lane);
          #pragma unroll
          for (int r = 0; r < 8; ++r){
            u64 m = p0 > p1 ? p0 : p1;
            #pragma unroll
            for (int o = 32; o; o >>= 1){ u64 q = __shfl_xor(m, o); if (q > m) m = q; }
            if (p0 == m) p0 = 0; else if (p1 == m) p1 = 0;
            if (lane == 0) astoreu64(cand + (((size_t)b_s*8 + key)*8 + rg)*8 + r, m);
          }
        }
      }
      DRAIN();
      __syncthreads();
      if (tid == 0) astoreu32(arrv + LF_FC(wg), (uint)(t+1));
      // ---- gp(t) for h(t+1): overlapped with batch merge ----
      float gpv;
      {
        float a0 = G_emb[(size_t)((t+1)*BQ + gb)*2048 + pcol];
        float a1 = 0.f, a2 = 0.f, a3 = 0.f;
        const float4* wh = (const float4*)(W_hh + (size_t)rrow*HID);
        const float4* xv = (const float4*)(hs + gb*516);
        #pragma unroll 2
        for (int k = 0; k < 128; k += 4){
          float4 w, x;
          w=wh[k+0]; x=xv[k+0]; a0=fmaf(w.x,x.x,a0); a0=fmaf(w.y,x.y,a0); a0=fmaf(w.z,x.z,a0); a0=fmaf(w.w,x.w,a0);
          w=wh[k+1]; x=xv[k+1]; a1=fmaf(w.x,x.x,a1); a1=fmaf(w.y,x.y,a1); a1=fmaf(w.z,x.z,a1); a1=fmaf(w.w,x.w,a1);
          w=wh[k+2]; x=xv[k+2]; a2=fmaf(w.x,x.x,a2); a2=fmaf(w.y,x.y,a2); a2=fmaf(w.z,x.z,a2); a2=fmaf(w.w,x.w,a2);
          w=wh[k+3]; x=xv[k+3]; a3=fmaf(w.x,x.x,a3); a3=fmaf(w.y,x.y,a3); a3=fmaf(w.z,x.z,a3); a3=fmaf(w.w,x.w,a3);
        }
        gpv = (a0+a1)+(a2+a3);
      }
      // ---- wait rv (16 producers), finish gates, publish ----
      if (tid < 16) poll1(arrv + LF_FRV(tid), (uint)(t+1));
      __syncthreads();
      {
        float4 v; AL4(v, (const float4*)rvpub + tid); AWAIT();
        *(float4*)(rv_s + tid*4) = v;
      }
      __syncthreads();
      {
        float acc = gpv;
        #pragma unroll 8
        for (int d = 0; d < 64; ++d)
          acc = fmaf(rv_s[gb*64 + d], WT_s[d*16 + gc], acc);
        astoref(gatespub + (size_t)gb*2048 + pcol, acc);
      }
      DRAIN();
      __syncthreads();
      if (tid == 0) astoreu32(arrv + LF_FG(wg), (uint)(t+1));
    }
  } else {
    // =================== BATCH WG ===================
    const int b = wg - NWK;
    float* rv_st = smem;                 // [4][64] scratch
    // prologue: h(0) from G_emb[0] (c=h=rv=0), packed (i,f,g,o) per unit
    float c0, c1;
    {
      float4 gA = *(const float4*)(G_emb + (size_t)b*2048 + tid*8);
      float4 gB = *(const float4*)(G_emb + (size_t)b*2048 + tid*8 + 4);
      c0 = sigm(gA.x)*tanhf(gA.z);
      float h0v = sigm(gA.w)*tanhf(c0);
      c1 = sigm(gB.x)*tanhf(gB.z);
      float h1v = sigm(gB.w)*tanhf(c1);
      astoref(H_pub + (size_t)b*HID + tid*2,     h0v);
      astoref(H_pub + (size_t)b*HID + tid*2 + 1, h1v);
      H_all[(size_t)b*HID + tid*2]     = h0v;    // plain: consumed by next kernel
      H_all[(size_t)b*HID + tid*2 + 1] = h1v;
    }
    DRAIN();
    __syncthreads();
    if (tid == 0) astoreu32(arrv + LF_FH(b), 1u);

    #pragma clang loop unroll(disable)
    for (int t = 0; t < T_STEPS-1; ++t){
      // ---- wait my 8 slot-WGs' candidates ----
      if (tid < 8) poll1(arrv + LF_FC(b*8 + tid), (uint)(t+1));
      __syncthreads();
      // ---- merge top8 per key, softmax, rv gather, wlist (R4 P4) ----
      {
        int wid = tid >> 6, lane = tid & 63;
        #pragma unroll
        for (int kk = 0; kk < 2; ++kk){
          int key = wid*2 + kk;
          u64 pv = aloadu64(cand + (((size_t)b*8 + key)*8 + (lane >> 3))*8 + (lane & 7));
          u64 sel = 0;
          #pragma unroll
          for (int r = 0; r < 8; ++r){
            u64 m = pv;
            #pragma unroll
            for (int o = 32; o; o >>= 1){ u64 q = __shfl_xor(m, o); if (q > m) m = q; }
            if (pv == m) pv = 0;
            if (lane == r) sel = m;
          }
          float val = unpackval(sel);
          int slot = unpackslot(sel);
          float vmax = __shfl(val, 0);
          float e = (lane < 8) ? expf(val - vmax) : 0.f;
          float ssum = e;
          #pragma unroll
          for (int o = 32; o; o >>= 1) ssum += __shfl_xor(ssum, o);
          float w = e / ssum;
          if (key < 4){
            int sls[8];
            #pragma unroll
            for (int i = 0; i < 8; ++i) sls[i] = __shfl(slot, i);
            float mv[8];
            #pragma unroll
            for (int i = 0; i < 8; ++i)
              ALF(mv[i], mem_g + ((size_t)b*NSLOT + sls[i])*MD + lane);
            AWAIT();
            float acc = 0.f;
            #pragma unroll
            for (int i = 0; i < 8; ++i) acc = fmaf(__shfl(w, i), mv[i], acc);
            rv_st[key*64 + lane] = acc;
          } else if (lane < 8){
            astoreu64(wlist + (size_t)b*32 + (key-4)*8 + lane,
                      ((u64)__float_as_uint(w) << 32) | (u64)(uint)slot);
          }
        }
      }
      __syncthreads();
      if (tid < 64){
        float m = 0.25f*(rv_st[tid] + rv_st[64+tid] + rv_st[128+tid] + rv_st[192+tid]);
        astoref(rvpub + (size_t)b*MD + tid, m);
      }
      DRAIN();
      __syncthreads();
      if (tid == 0) astoreu32(arrv + LF_FRV(b), (uint)(t+1));
      // ---- wait all 128 gate chunks; LSTM; publish h(t+1) ----
      if (tid < 128) poll1(arrv + LF_FG(tid), (uint)(t+1));
      __syncthreads();
      {
        float4 gA, gB;
        AL4(gA, (const float4*)(gatespub + (size_t)b*2048) + tid*2);
        AL4(gB, (const float4*)(gatespub + (size_t)b*2048) + tid*2 + 1);
        AWAIT();
        c0 = sigm(gA.y)*c0 + sigm(gA.x)*tanhf(gA.z);
        float h0v = sigm(gA.w)*tanhf(c0);
        c1 = sigm(gB.y)*c1 + sigm(gB.x)*tanhf(gB.z);
        float h1v = sigm(gB.w)*tanhf(c1);
        astoref(H_pub + (size_t)b*HID + tid*2,     h0v);
        astoref(H_pub + (size_t)b*HID + tid*2 + 1, h1v);
        H_all[(size_t)((t+1)*BQ + b)*HID + tid*2]     = h0v;
        H_all[(size_t)((t+1)*BQ + b)*HID + tid*2 + 1] = h1v;
      }
      DRAIN();
      __syncthreads();
      if (tid == 0) astoreu32(arrv + LF_FH(b), (uint)(t+2));
    }
  }
}

// ---------------- phase B: logits = H_all[2048,512] @ W_out[512,32000] + b_out ----------------
__global__ __launch_bounds__(256) void gemm_out(const float* __restrict__ A,
                                                const float* __restrict__ Bmat,
                                                const float* __restrict__ bias,
                                                float* __restrict__ C){
  __shared__ __align__(16) float As[16*132];
  __shared__ __align__(16) float Bs[16*64];
  int mt = blockIdx.x & 15, nt = blockIdx.x >> 4;
  int m0 = mt*128, n0 = nt*64;
  int tx = threadIdx.x & 15, ty = threadIdx.x >> 4;
  float acc[8][4] = {};
  for (int k0 = 0; k0 < 512; k0 += 16){
    int mm = threadIdx.x >> 1, kq = (threadIdx.x & 1)*8;
    float4 a0 = *(const float4*)(A + (size_t)(m0+mm)*512 + k0 + kq);
    float4 a1 = *(const float4*)(A + (size_t)(m0+mm)*512 + k0 + kq + 4);
    As[(kq+0)*132+mm]=a0.x; As[(kq+1)*132+mm]=a0.y; As[(kq+2)*132+mm]=a0.z; As[(kq+3)*132+mm]=a0.w;
    As[(kq+4)*132+mm]=a1.x; As[(kq+5)*132+mm]=a1.y; As[(kq+6)*132+mm]=a1.z; As[(kq+7)*132+mm]=a1.w;
    int kk2 = threadIdx.x >> 4, nq = (threadIdx.x & 15)*4;
    *(float4*)(Bs + kk2*64 + nq) = *(const float4*)(Bmat + (size_t)(k0+kk2)*VOCAB + n0 + nq);
    __syncthreads();
    #pragma unroll
    for (int kk = 0; kk < 16; ++kk){
      float4 x0 = *(const float4*)(As + kk*132 + ty*8);
      float4 x1 = *(const float4*)(As + kk*132 + ty*8 + 4);
      float4 bv = *(const float4*)(Bs + kk*64 + tx*4);
      float aa[8] = {x0.x,x0.y,x0.z,x0.w,x1.x,x1.y,x1.z,x1.w};
      float bb[4] = {bv.x,bv.y,bv.z,bv.w};
      #pragma unroll
      for (int i = 0; i < 8; ++i)
        #pragma unroll
        for (int j = 0; j < 4; ++j)
          acc[i][j] = fmaf(aa[i], bb[j], acc[i][j]);
    }
    __syncthreads();
  }
  #pragma unroll
  for (int i = 0; i < 8; ++i){
    int m = m0 + ty*8 + i;
    int bq = m & 15, tt = m >> 4;
    float* crow = C + ((size_t)bq*T_STEPS + tt)*VOCAB + n0 + tx*4;
    #pragma unroll
    for (int j = 0; j < 4; ++j) crow[j] = acc[i][j] + bias[n0 + tx*4 + j];
  }
}

extern "C" void kernel_launch(void* const* d_in, const int* in_sizes, int n_in,
                              void* d_out, int out_size, void* d_ws, size_t ws_size,
                              hipStream_t stream){
  const int*   seq   = (const int*)d_in[0];
  const float* E     = (const float*)d_in[1];
  const float* W_ih  = (const float*)d_in[2];
  const float* W_hh  = (const float*)d_in[3];
  const float* b_ih  = (const float*)d_in[4];
  const float* b_hh  = (const float*)d_in[5];
  const float* W_out = (const float*)d_in[6];
  const float* b_out = (const float*)d_in[7];
  const float* W_rk  = (const float*)d_in[8];
  const float* b_rk  = (const float*)d_in[9];
  const float* W_wk  = (const float*)d_in[10];
  const float* b_wk  = (const float*)d_in[11];
  const float* W_wv  = (const float*)d_in[12];
  const float* b_wv  = (const float*)d_in[13];
  const float* W_er  = (const float*)d_in[14];
  const float* b_er  = (const float*)d_in[15];
  float* out = (float*)d_out;
  (void)in_sizes; (void)n_in; (void)out_size; (void)ws_size;

  char* ws = (char*)d_ws;
  size_t off = 0;
  auto alloc = [&](size_t bytes) -> void* {
    off = (off + 255) & ~(size_t)255;
    void* p = ws + off;
    off += bytes;
    return p;
  };
  float* EMB      = (float*)alloc((size_t)2048*256*4);
  float* G_emb    = (float*)alloc((size_t)2048*2048*4);
  float* H_all    = (float*)alloc((size_t)2048*512*4);
  float* H_pub    = (float*)alloc((size_t)16*512*4);
  float* mem_g    = (float*)alloc((size_t)16*1024*64*4);
  float* projpub  = (float*)alloc((size_t)2*16*1024*4);
  float* gatespub = (float*)alloc((size_t)16*2048*4);
  float* rvpub    = (float*)alloc((size_t)16*64*4);
  u64*   cand     = (u64*)alloc((size_t)16*8*8*8*8);
  u64*   wlist    = (u64*)alloc((size_t)16*32*8);
  float* WT       = (float*)alloc((size_t)64*2048*4);
  uint*  arrv     = (uint*)alloc((size_t)NLINES*32*4);

  hipMemsetAsync(arrv, 0, (size_t)NLINES*32*4, stream);   // flags zero each replay
  prep_emb<<<2048, 256, 0, stream>>>(E, seq, EMB);
  gemm_emb<<<1024, 256, 0, stream>>>(EMB, W_ih, b_ih, b_hh, G_emb);
  make_wrvT<<<512, 256, 0, stream>>>(W_ih, WT);
  recur_kernel<<<NWK + NBT, 256, 0, stream>>>(
      W_hh, WT, W_rk, b_rk, W_wk, b_wk, W_wv, b_wv, W_er, b_er,
      G_emb, H_all, H_pub, mem_g, projpub, gatespub, rvpub, cand, wlist, arrv);
  gemm_out<<<16*500, 256, 0, stream>>>(H_all, W_out, b_out, out);
}